// Round 1
// baseline (3880.499 us; speedup 1.0000x reference)
//
#include <hip/hip_runtime.h>

typedef __attribute__((ext_vector_type(8)))  short short8;
typedef __attribute__((ext_vector_type(4)))  float f32x4;
typedef __attribute__((ext_vector_type(16))) float f32x16;

#define L0    8192
#define LFIN  4612
#define PSKIP 3580   // L0 - LFIN

static const int DILS[39] = {
  1,2,4,8,16,32,64,128,256,512,
  1,2,4,8,16,32,64,128,256,512,
  1,2,4,8,16,32,64,128,256,512,
  1,2,4,8,16,32,64,128,256};

__device__ __forceinline__ unsigned short f2bf(float f) {
  unsigned u = __builtin_bit_cast(unsigned, f);
  u += 0x7fffu + ((u >> 16) & 1u);          // RNE
  return (unsigned short)(u >> 16);
}
__device__ __forceinline__ float bf2f(unsigned short h) {
  return __builtin_bit_cast(float, (unsigned)h << 16);
}

// ---------------- weight conversion f32 -> bf16 (once per call) ----------------
// Wd layout: [layer][co 256][k 256], k = tap*128 + ci  (tap0 @ p-d, tap1 @ p)
__global__ __launch_bounds__(256) void wconv_kernel(
    const float* __restrict__ dw, const float* __restrict__ rw,
    const float* __restrict__ sw, const float* __restrict__ ew,
    unsigned short* __restrict__ Wd, unsigned short* __restrict__ Wr,
    unsigned short* __restrict__ Ws, unsigned short* __restrict__ We)
{
  int e = blockIdx.x * 256 + threadIdx.x;
  const int ND = 39*65536, NR = 39*16384, NS = 39*32768, NE = 16384;
  if (e < ND) {
    int i = e >> 16, r = e & 65535;
    int co = r >> 8, k = r & 255;
    int tap = k >> 7, ci = k & 127;
    Wd[e] = f2bf(dw[(((size_t)i*256 + co)*128 + ci)*2 + tap]);
  } else if ((e -= ND) < NR) {
    Wr[e] = f2bf(rw[e]);
  } else if ((e -= NR) < NS) {
    Ws[e] = f2bf(sw[e]);
  } else if ((e -= NS) < NE) {
    We[e] = f2bf(ew[e]);
  }
}

// ---------------- start: 1x1 conv 40 -> 128, position-major bf16 output ----------------
__global__ __launch_bounds__(256) void start_kernel(
    const float* __restrict__ x, const float* __restrict__ w,
    const float* __restrict__ b, unsigned short* __restrict__ H)
{
  __shared__ float xs[40][64];
  __shared__ float wl[128*41];
  const int tid = threadIdx.x;
  const int n = blockIdx.y;
  const int p0 = blockIdx.x * 64;

  for (int e = tid; e < 40*64; e += 256) {
    int ci = e >> 6, t = e & 63;
    xs[ci][t] = x[((size_t)n*40 + ci)*L0 + p0 + t];
  }
  for (int e = tid; e < 128*40; e += 256)
    wl[(e/40)*41 + (e%40)] = w[e];
  __syncthreads();

  const int c  = tid & 127;
  const int ph = tid >> 7;                 // 0..1
  const float bias = b[c];
  #pragma unroll 4
  for (int k = 0; k < 32; ++k) {
    int p = ph + 2*k;
    float acc = bias;
    #pragma unroll
    for (int ci = 0; ci < 40; ++ci)
      acc = fmaf(wl[c*41 + ci], xs[ci][p], acc);
    H[((size_t)n*L0 + p0 + p)*128 + c] = f2bf(acc);
  }
}

// ---------------- one gated residual layer, 32x32x16 MFMA ----------------
// H: bf16 position-major [n][8192][128], right-aligned.
// taps LDS [64 p][256 k] bf16, swizzled: byte = (p*512 + 2k) ^ ((p&7)<<4)
// MFMA operand order: D[p in regs][co in lanes] = mfma(taps_frag, W_frag)
// so all global epilogue accesses are lane-contiguous in channel.
__global__ __launch_bounds__(256) void layer_mfma(
    const unsigned short* __restrict__ Hin, unsigned short* __restrict__ Hout,
    float* __restrict__ SK,
    const unsigned short* __restrict__ Wd, const float* __restrict__ db,
    const unsigned short* __restrict__ Wr, const float* __restrict__ rb,
    const unsigned short* __restrict__ Ws, const float* __restrict__ sb,
    int d, int Lout, int accum)
{
  __shared__ unsigned short taps[64*256];   // 32 KiB

  const int tid = threadIdx.x;
  const int n = blockIdx.y;
  const int p0 = (L0 - Lout) + blockIdx.x * 64;
  const unsigned short* __restrict__ Hn = Hin + (size_t)n * L0 * 128;

  // ---- stage taps: global bf16 -> LDS (swizzled), 16B per lane ----
  #pragma unroll
  for (int it = 0; it < 8; ++it) {
    int e = it * 256 + tid;          // 0..2047
    int c8  = (e & 15) << 3;         // ci 0..120 step 8
    int p   = (e >> 4) & 63;
    int tap = e >> 10;
    int gp = p0 + p - (tap ? 0 : d);
    if (gp > L0 - 1) gp = L0 - 1;    // p0 >= d always, so gp >= 0
    short8 v = *(const short8*)&Hn[(size_t)gp * 128 + c8];
    int byte = ((p << 9) + (((tap << 7) + c8) << 1)) ^ ((p & 7) << 4);
    *(short8*)((char*)taps + byte) = v;
  }
  __syncthreads();

  const int w  = tid >> 6, lane = tid & 63;
  const int ln = lane & 31, hi = lane >> 5;
  const f32x16 fz16 = {0.f};

  const float bf_s = db[32*w + ln];
  const float bg_s = db[128 + 32*w + ln];

  // ---- GEMM1: dilated conv, D[64 p][256 co], K=256 ----
  // wave w: co lanes f = 32w+ln, g = 128+32w+ln; p tiles nb=0,1 (regs)
  f32x16 af[2] = {fz16, fz16}, ag[2] = {fz16, fz16};
  #pragma unroll
  for (int ks = 0; ks < 16; ++ks) {
    int kb = ks*32 + hi*16;                     // byte offset of k-chunk
    short8 A0 = *(const short8*)((const char*)taps + (((ln << 9) + kb) ^ ((ln & 7) << 4)));
    short8 A1 = *(const short8*)((const char*)taps + ((((32 + ln) << 9) + kb) ^ ((ln & 7) << 4)));
    short8 Bf = *(const short8*)&Wd[(size_t)(32*w + ln) * 256 + ks*16 + hi*8];
    short8 Bg = *(const short8*)&Wd[(size_t)(128 + 32*w + ln) * 256 + ks*16 + hi*8];
    af[0] = __builtin_amdgcn_mfma_f32_32x32x16_bf16(A0, Bf, af[0], 0, 0, 0);
    af[1] = __builtin_amdgcn_mfma_f32_32x32x16_bf16(A1, Bf, af[1], 0, 0, 0);
    ag[0] = __builtin_amdgcn_mfma_f32_32x32x16_bf16(A0, Bg, ag[0], 0, 0, 0);
    ag[1] = __builtin_amdgcn_mfma_f32_32x32x16_bf16(A1, Bg, ag[1], 0, 0, 0);
  }

  // ---- gate in registers; D row(p) = (reg&3)+8*(reg>>2)+4*hi, col(co) = ln ----
  __syncthreads();     // all waves done reading taps (tap0 about to be overwritten)
  #pragma unroll
  for (int nb = 0; nb < 2; ++nb) {
    #pragma unroll
    for (int rr = 0; rr < 16; ++rr) {
      int pl = nb*32 + (rr & 3) + 8*(rr >> 2) + 4*hi;
      float fv = af[nb][rr] + bf_s;
      float gg = ag[nb][rr] + bg_s;
      float th = 2.f * __builtin_amdgcn_rcpf(1.f + __expf(-2.f * fv)) - 1.f;
      float sg = __builtin_amdgcn_rcpf(1.f + __expf(-gg));
      int byte = ((pl << 9) + ((32*w + ln) << 1)) ^ ((pl & 7) << 4);
      *(unsigned short*)((char*)taps + byte) = f2bf(th * sg);
    }
  }
  __syncthreads();

  // ---- load all gated A fragments (K=128 -> 8 ks), reused by 3 output passes ----
  short8 Ag2[2][8];
  #pragma unroll
  for (int nb = 0; nb < 2; ++nb) {
    int p = nb*32 + ln;
    #pragma unroll
    for (int ks = 0; ks < 8; ++ks)
      Ag2[nb][ks] = *(const short8*)((const char*)taps +
                     (((p << 9) + ks*32 + hi*16) ^ ((p & 7) << 4)));
  }

  float* SKn = SK + (size_t)n * LFIN * 256;
  unsigned short* Hon = Hout + (size_t)n * L0 * 128;

  // ---- passes 0,1: skip co = 32w+128t+ln (skip entirely if block below PSKIP) ----
  if (p0 + 63 >= PSKIP) {
    #pragma unroll
    for (int t = 0; t < 2; ++t) {
      const unsigned short* Bw = Ws + (size_t)(32*w + 128*t) * 128;
      const float bs = sb[32*w + 128*t + ln];
      f32x16 acc[2] = {fz16, fz16};
      #pragma unroll
      for (int ks = 0; ks < 8; ++ks) {
        short8 B = *(const short8*)&Bw[(size_t)ln * 128 + ks*16 + hi*8];
        acc[0] = __builtin_amdgcn_mfma_f32_32x32x16_bf16(Ag2[0][ks], B, acc[0], 0, 0, 0);
        acc[1] = __builtin_amdgcn_mfma_f32_32x32x16_bf16(Ag2[1][ks], B, acc[1], 0, 0, 0);
      }
      #pragma unroll
      for (int nb = 0; nb < 2; ++nb) {
        #pragma unroll
        for (int rr = 0; rr < 16; ++rr) {
          int p = p0 + nb*32 + (rr & 3) + 8*(rr >> 2) + 4*hi;
          if (p >= PSKIP && p < L0) {
            float* dst = &SKn[(size_t)(p - PSKIP) * 256 + 32*w + 128*t + ln];
            float v = acc[nb][rr] + bs;
            if (accum) v += *dst;
            *dst = v;
          }
        }
      }
    }
  }
  // ---- pass 2: res co = 32w+ln ----
  {
    const unsigned short* Bw = Wr + (size_t)(32*w) * 128;
    const float br = rb[32*w + ln];
    f32x16 acc[2] = {fz16, fz16};
    #pragma unroll
    for (int ks = 0; ks < 8; ++ks) {
      short8 B = *(const short8*)&Bw[(size_t)ln * 128 + ks*16 + hi*8];
      acc[0] = __builtin_amdgcn_mfma_f32_32x32x16_bf16(Ag2[0][ks], B, acc[0], 0, 0, 0);
      acc[1] = __builtin_amdgcn_mfma_f32_32x32x16_bf16(Ag2[1][ks], B, acc[1], 0, 0, 0);
    }
    #pragma unroll
    for (int nb = 0; nb < 2; ++nb) {
      #pragma unroll
      for (int rr = 0; rr < 16; ++rr) {
        int pl = nb*32 + (rr & 3) + 8*(rr >> 2) + 4*hi;
        int p = p0 + pl;
        if (p < L0) {
          // residual from LDS tap1 (bf16 H at position p)
          int byteR = ((pl << 9) + ((128 + 32*w + ln) << 1)) ^ ((pl & 7) << 4);
          float hres = bf2f(*(const unsigned short*)((const char*)taps + byteR));
          Hon[(size_t)p * 128 + 32*w + ln] = f2bf(acc[nb][rr] + br + hres);
        }
      }
    }
  }
}

// ---------------- end: relu + 1x1 conv 256 -> 64 (16x16 MFMA) ----------------
__global__ __launch_bounds__(256) void end_mfma(
    const float* __restrict__ SK, const unsigned short* __restrict__ We,
    const float* __restrict__ eb, float* __restrict__ out)
{
  __shared__ unsigned short sl[64*256];
  const int tid = threadIdx.x;
  const int n = blockIdx.y;
  const int p0 = blockIdx.x * 64;
  const float* __restrict__ SKn = SK + (size_t)n * LFIN * 256;

  #pragma unroll
  for (int it = 0; it < 16; ++it) {
    int e = it * 256 + tid;
    int c4 = (e & 63) << 2;
    int p  = e >> 6;
    int gp = p0 + p; if (gp > LFIN - 1) gp = LFIN - 1;
    float4 v = *(const float4*)&SKn[(size_t)gp * 256 + c4];
    ushort4 h;
    h.x = f2bf(fmaxf(v.x, 0.f)); h.y = f2bf(fmaxf(v.y, 0.f));
    h.z = f2bf(fmaxf(v.z, 0.f)); h.w = f2bf(fmaxf(v.w, 0.f));
    int byte = ((p << 9) + (c4 << 1)) ^ ((p & 7) << 4);
    *(ushort4*)((char*)sl + byte) = h;
  }
  __syncthreads();

  const int w  = tid >> 6, lane = tid & 63;
  const int lr = lane & 15, lg = lane >> 4;
  const f32x4 fz = {0.f, 0.f, 0.f, 0.f};
  f32x4 acc[4] = {fz, fz, fz, fz};

  #pragma unroll
  for (int ks = 0; ks < 8; ++ks) {
    short8 A = *(const short8*)&We[(size_t)(16*w + lr) * 256 + ks*32 + lg*8];
    #pragma unroll
    for (int nb = 0; nb < 4; ++nb) {
      int p = nb * 16 + lr;
      int byte = ((p << 9) + ((ks*32 + lg*8) << 1)) ^ ((p & 7) << 4);
      short8 B = *(const short8*)((const char*)sl + byte);
      acc[nb] = __builtin_amdgcn_mfma_f32_16x16x32_bf16(A, B, acc[nb], 0, 0, 0);
    }
  }
  #pragma unroll
  for (int nb = 0; nb < 4; ++nb) {
    int p = p0 + nb*16 + lr;
    if (p < LFIN) {
      #pragma unroll
      for (int r = 0; r < 4; ++r) {
        int co = 16*w + lg*4 + r;
        out[((size_t)n*64 + co) * LFIN + p] = acc[nb][r] + eb[co];
      }
    }
  }
}

// ---------------- host ----------------
extern "C" void kernel_launch(void* const* d_in, const int* in_sizes, int n_in,
                              void* d_out, int out_size, void* d_ws, size_t ws_size,
                              hipStream_t stream)
{
  const float* x      = (const float*)d_in[0];
  const float* startw = (const float*)d_in[1];
  const float* startb = (const float*)d_in[2];
  const float* dilw   = (const float*)d_in[3];
  const float* dilb   = (const float*)d_in[4];
  const float* resw   = (const float*)d_in[5];
  const float* resb   = (const float*)d_in[6];
  const float* skipw  = (const float*)d_in[7];
  const float* skipb  = (const float*)d_in[8];
  const float* endw   = (const float*)d_in[9];
  const float* endb   = (const float*)d_in[10];

  unsigned short* H0 = (unsigned short*)d_ws;       // [8][8192][128] bf16 pos-major
  unsigned short* H1 = H0 + (size_t)8*L0*128;
  float* SK = (float*)(H1 + (size_t)8*L0*128);      // [8][4612][256] f32 pos-major
  unsigned short* Wd = (unsigned short*)(SK + (size_t)8*LFIN*256);
  unsigned short* Wr = Wd + (size_t)39*65536;
  unsigned short* Ws = Wr + (size_t)39*16384;
  unsigned short* We = Ws + (size_t)39*32768;

  const int total = 39*65536 + 39*16384 + 39*32768 + 16384;
  wconv_kernel<<<(total + 255)/256, 256, 0, stream>>>(dilw, resw, skipw, endw, Wd, Wr, Ws, We);
  start_kernel<<<dim3(L0/64, 8), 256, 0, stream>>>(x, startw, startb, H0);

  unsigned short* bufs[2] = {H0, H1};
  int cur = 0, L = L0;
  for (int i = 0; i < 39; ++i) {
    int d = DILS[i];
    int Lout = L - d;
    dim3 grid((Lout + 63) / 64, 8);
    layer_mfma<<<grid, 256, 0, stream>>>(bufs[cur], bufs[cur ^ 1], SK,
        Wd + (size_t)i*65536, dilb + (size_t)i*256,
        Wr + (size_t)i*16384, resb + (size_t)i*128,
        Ws + (size_t)i*32768, skipb + (size_t)i*256,
        d, Lout, i ? 1 : 0);
    cur ^= 1;
    L = Lout;
  }

  end_mfma<<<dim3((LFIN + 63)/64, 8), 256, 0, stream>>>(SK, We, endb, (float*)d_out);
}

// Round 2
// 3415.075 us; speedup vs baseline: 1.1363x; 1.1363x over previous
//
#include <hip/hip_runtime.h>

typedef __attribute__((ext_vector_type(8)))  short short8;
typedef __attribute__((ext_vector_type(4)))  float f32x4;
typedef __attribute__((ext_vector_type(16))) float f32x16;

#define L0    8192
#define LFIN  4612
#define PSKIP 3580   // L0 - LFIN

static const int DILS[39] = {
  1,2,4,8,16,32,64,128,256,512,
  1,2,4,8,16,32,64,128,256,512,
  1,2,4,8,16,32,64,128,256,512,
  1,2,4,8,16,32,64,128,256};

__device__ __forceinline__ unsigned short f2bf(float f) {
  unsigned u = __builtin_bit_cast(unsigned, f);
  u += 0x7fffu + ((u >> 16) & 1u);          // RNE
  return (unsigned short)(u >> 16);
}
__device__ __forceinline__ float bf2f(unsigned short h) {
  return __builtin_bit_cast(float, (unsigned)h << 16);
}

// ---------------- weight conversion f32 -> bf16 (once per call) ----------------
// Wd layout: [layer][co 256][k 256], k = tap*128 + ci  (tap0 @ p-d, tap1 @ p)
__global__ __launch_bounds__(256) void wconv_kernel(
    const float* __restrict__ dw, const float* __restrict__ rw,
    const float* __restrict__ sw, const float* __restrict__ ew,
    unsigned short* __restrict__ Wd, unsigned short* __restrict__ Wr,
    unsigned short* __restrict__ Ws, unsigned short* __restrict__ We)
{
  int e = blockIdx.x * 256 + threadIdx.x;
  const int ND = 39*65536, NR = 39*16384, NS = 39*32768, NE = 16384;
  if (e < ND) {
    int i = e >> 16, r = e & 65535;
    int co = r >> 8, k = r & 255;
    int tap = k >> 7, ci = k & 127;
    Wd[e] = f2bf(dw[(((size_t)i*256 + co)*128 + ci)*2 + tap]);
  } else if ((e -= ND) < NR) {
    Wr[e] = f2bf(rw[e]);
  } else if ((e -= NR) < NS) {
    Ws[e] = f2bf(sw[e]);
  } else if ((e -= NS) < NE) {
    We[e] = f2bf(ew[e]);
  }
}

// ---------------- start: 1x1 conv 40 -> 128, position-major bf16 output ----------------
__global__ __launch_bounds__(256) void start_kernel(
    const float* __restrict__ x, const float* __restrict__ w,
    const float* __restrict__ b, unsigned short* __restrict__ H)
{
  __shared__ float xs[40][64];
  __shared__ float wl[128*41];
  const int tid = threadIdx.x;
  const int n = blockIdx.y;
  const int p0 = blockIdx.x * 64;

  for (int e = tid; e < 40*64; e += 256) {
    int ci = e >> 6, t = e & 63;
    xs[ci][t] = x[((size_t)n*40 + ci)*L0 + p0 + t];
  }
  for (int e = tid; e < 128*40; e += 256)
    wl[(e/40)*41 + (e%40)] = w[e];
  __syncthreads();

  const int c  = tid & 127;
  const int ph = tid >> 7;                 // 0..1
  const float bias = b[c];
  #pragma unroll 4
  for (int k = 0; k < 32; ++k) {
    int p = ph + 2*k;
    float acc = bias;
    #pragma unroll
    for (int ci = 0; ci < 40; ++ci)
      acc = fmaf(wl[c*41 + ci], xs[ci][p], acc);
    H[((size_t)n*L0 + p0 + p)*128 + c] = f2bf(acc);
  }
}

// ---------------- one gated residual layer, 32x32x16 MFMA ----------------
// H: bf16 position-major [n][8192][128], right-aligned.
// taps LDS [64 p][256 k] bf16, swizzled: byte = (p*512 + 2k) ^ ((p&7)<<4)
// GEMM1 + gate: round-0 layout (A = weights, D[co regs][p lanes]) -- 84 VGPR proven.
// Epilogue GEMMs: operands swapped (A = gated taps, D[p regs][co lanes]) so all
// global SK/H accesses are lane-contiguous in channel (coalesced 128B segments).
__global__ __launch_bounds__(256) void layer_mfma(
    const unsigned short* __restrict__ Hin, unsigned short* __restrict__ Hout,
    float* __restrict__ SK,
    const unsigned short* __restrict__ Wd, const float* __restrict__ db,
    const unsigned short* __restrict__ Wr, const float* __restrict__ rb,
    const unsigned short* __restrict__ Ws, const float* __restrict__ sb,
    int d, int Lout, int accum)
{
  __shared__ unsigned short taps[64*256];   // 32 KiB

  const int tid = threadIdx.x;
  const int n = blockIdx.y;
  const int p0 = (L0 - Lout) + blockIdx.x * 64;
  const unsigned short* __restrict__ Hn = Hin + (size_t)n * L0 * 128;

  // ---- stage taps: global bf16 -> LDS (swizzled), 16B per lane ----
  #pragma unroll
  for (int it = 0; it < 8; ++it) {
    int e = it * 256 + tid;          // 0..2047
    int c8  = (e & 15) << 3;         // ci 0..120 step 8
    int p   = (e >> 4) & 63;
    int tap = e >> 10;
    int gp = p0 + p - (tap ? 0 : d);
    if (gp > L0 - 1) gp = L0 - 1;    // p0 >= d always, so gp >= 0
    short8 v = *(const short8*)&Hn[(size_t)gp * 128 + c8];
    int byte = ((p << 9) + (((tap << 7) + c8) << 1)) ^ ((p & 7) << 4);
    *(short8*)((char*)taps + byte) = v;
  }
  __syncthreads();

  const int w  = tid >> 6, lane = tid & 63;
  const int ln = lane & 31, hi = lane >> 5;
  const f32x16 fz16 = {0.f};

  // ---- GEMM1: dilated conv, D[256co regs][64p lanes], K=256 (round-0 order) ----
  f32x16 af[2] = {fz16, fz16}, ag[2] = {fz16, fz16};
  #pragma unroll
  for (int ks = 0; ks < 16; ++ks) {
    int kb = ks*32 + hi*16;                     // byte offset of k-chunk
    int pA = ln, pB = 32 + ln;
    short8 B0 = *(const short8*)((const char*)taps + (((pA << 9) + kb) ^ ((pA & 7) << 4)));
    short8 B1 = *(const short8*)((const char*)taps + (((pB << 9) + kb) ^ ((pB & 7) << 4)));
    short8 Af = *(const short8*)&Wd[(size_t)(32*w + ln) * 256 + ks*16 + hi*8];
    short8 Ag = *(const short8*)&Wd[(size_t)(128 + 32*w + ln) * 256 + ks*16 + hi*8];
    af[0] = __builtin_amdgcn_mfma_f32_32x32x16_bf16(Af, B0, af[0], 0, 0, 0);
    af[1] = __builtin_amdgcn_mfma_f32_32x32x16_bf16(Af, B1, af[1], 0, 0, 0);
    ag[0] = __builtin_amdgcn_mfma_f32_32x32x16_bf16(Ag, B0, ag[0], 0, 0, 0);
    ag[1] = __builtin_amdgcn_mfma_f32_32x32x16_bf16(Ag, B1, ag[1], 0, 0, 0);
  }

  // ---- gate in registers (round-0); D row(co) = (reg&3)+8*(reg>>2)+4*hi, col(p) = ln ----
  __syncthreads();     // all waves done reading taps (tap0 about to be overwritten)
  #pragma unroll
  for (int nb = 0; nb < 2; ++nb) {
    int p = nb*32 + ln;
    #pragma unroll
    for (int q = 0; q < 4; ++q) {
      int rbase = 8*q + 4*hi;
      const float4 bf4 = *(const float4*)&db[32*w + rbase];
      const float4 bg4 = *(const float4*)&db[128 + 32*w + rbase];
      const float bfv[4] = {bf4.x, bf4.y, bf4.z, bf4.w};
      const float bgv[4] = {bg4.x, bg4.y, bg4.z, bg4.w};
      unsigned short gs[4];
      #pragma unroll
      for (int r = 0; r < 4; ++r) {
        float fv = af[nb][4*q + r] + bfv[r];
        float gg = ag[nb][4*q + r] + bgv[r];
        float th = 2.f * __builtin_amdgcn_rcpf(1.f + __expf(-2.f * fv)) - 1.f;
        float sg = __builtin_amdgcn_rcpf(1.f + __expf(-gg));
        gs[r] = f2bf(th * sg);
      }
      ushort4 gv; gv.x = gs[0]; gv.y = gs[1]; gv.z = gs[2]; gv.w = gs[3];
      int byte = ((p << 9) + ((32*w + rbase) << 1)) ^ ((p & 7) << 4);
      *(ushort4*)((char*)taps + byte) = gv;
    }
  }
  __syncthreads();

  // ---- load all gated fragments (K=128 -> 8 ks), reused by 3 output passes ----
  // Same bits serve as A-operand (row = p = ln+32nb) in the swapped epilogue GEMMs.
  short8 Bg[2][8];
  #pragma unroll
  for (int nb = 0; nb < 2; ++nb) {
    int p = nb*32 + ln;
    #pragma unroll
    for (int ks = 0; ks < 8; ++ks)
      Bg[nb][ks] = *(const short8*)((const char*)taps +
                     (((p << 9) + ks*32 + hi*16) ^ ((p & 7) << 4)));
  }

  float* SKn = SK + (size_t)n * LFIN * 256;
  unsigned short* Hon = Hout + (size_t)n * L0 * 128;

  // ---- passes 0,1: skip co = 32w+128t+ln (elided if block entirely below PSKIP) ----
  if (p0 + 63 >= PSKIP) {
    #pragma unroll
    for (int t = 0; t < 2; ++t) {
      const unsigned short* Bw = Ws + (size_t)(32*w + 128*t) * 128;
      const float bs = sb[32*w + 128*t + ln];
      f32x16 acc[2] = {fz16, fz16};
      #pragma unroll
      for (int ks = 0; ks < 8; ++ks) {
        short8 B = *(const short8*)&Bw[(size_t)ln * 128 + ks*16 + hi*8];
        acc[0] = __builtin_amdgcn_mfma_f32_32x32x16_bf16(Bg[0][ks], B, acc[0], 0, 0, 0);
        acc[1] = __builtin_amdgcn_mfma_f32_32x32x16_bf16(Bg[1][ks], B, acc[1], 0, 0, 0);
      }
      #pragma unroll
      for (int nb = 0; nb < 2; ++nb) {
        #pragma unroll
        for (int rr = 0; rr < 16; ++rr) {
          int p = p0 + nb*32 + (rr & 3) + 8*(rr >> 2) + 4*hi;
          if (p >= PSKIP && p < L0) {
            float* dst = &SKn[(size_t)(p - PSKIP) * 256 + 32*w + 128*t + ln];
            float v = acc[nb][rr] + bs;
            if (accum) v += *dst;
            *dst = v;
          }
        }
      }
    }
  }
  // ---- pass 2: res co = 32w+ln ----
  {
    const unsigned short* Bw = Wr + (size_t)(32*w) * 128;
    const float br = rb[32*w + ln];
    f32x16 acc[2] = {fz16, fz16};
    #pragma unroll
    for (int ks = 0; ks < 8; ++ks) {
      short8 B = *(const short8*)&Bw[(size_t)ln * 128 + ks*16 + hi*8];
      acc[0] = __builtin_amdgcn_mfma_f32_32x32x16_bf16(Bg[0][ks], B, acc[0], 0, 0, 0);
      acc[1] = __builtin_amdgcn_mfma_f32_32x32x16_bf16(Bg[1][ks], B, acc[1], 0, 0, 0);
    }
    #pragma unroll
    for (int nb = 0; nb < 2; ++nb) {
      #pragma unroll
      for (int rr = 0; rr < 16; ++rr) {
        int pl = nb*32 + (rr & 3) + 8*(rr >> 2) + 4*hi;
        int p = p0 + pl;
        if (p < L0) {
          // residual from LDS tap1 (bf16 H at position p); lanes read contiguous co: conflict-free
          int byteR = ((pl << 9) + ((128 + 32*w + ln) << 1)) ^ ((pl & 7) << 4);
          float hres = bf2f(*(const unsigned short*)((const char*)taps + byteR));
          Hon[(size_t)p * 128 + 32*w + ln] = f2bf(acc[nb][rr] + br + hres);
        }
      }
    }
  }
}

// ---------------- end: relu + 1x1 conv 256 -> 64 (16x16 MFMA) ----------------
__global__ __launch_bounds__(256) void end_mfma(
    const float* __restrict__ SK, const unsigned short* __restrict__ We,
    const float* __restrict__ eb, float* __restrict__ out)
{
  __shared__ unsigned short sl[64*256];
  const int tid = threadIdx.x;
  const int n = blockIdx.y;
  const int p0 = blockIdx.x * 64;
  const float* __restrict__ SKn = SK + (size_t)n * LFIN * 256;

  #pragma unroll
  for (int it = 0; it < 16; ++it) {
    int e = it * 256 + tid;
    int c4 = (e & 63) << 2;
    int p  = e >> 6;
    int gp = p0 + p; if (gp > LFIN - 1) gp = LFIN - 1;
    float4 v = *(const float4*)&SKn[(size_t)gp * 256 + c4];
    ushort4 h;
    h.x = f2bf(fmaxf(v.x, 0.f)); h.y = f2bf(fmaxf(v.y, 0.f));
    h.z = f2bf(fmaxf(v.z, 0.f)); h.w = f2bf(fmaxf(v.w, 0.f));
    int byte = ((p << 9) + (c4 << 1)) ^ ((p & 7) << 4);
    *(ushort4*)((char*)sl + byte) = h;
  }
  __syncthreads();

  const int w  = tid >> 6, lane = tid & 63;
  const int lr = lane & 15, lg = lane >> 4;
  const f32x4 fz = {0.f, 0.f, 0.f, 0.f};
  f32x4 acc[4] = {fz, fz, fz, fz};

  #pragma unroll
  for (int ks = 0; ks < 8; ++ks) {
    short8 A = *(const short8*)&We[(size_t)(16*w + lr) * 256 + ks*32 + lg*8];
    #pragma unroll
    for (int nb = 0; nb < 4; ++nb) {
      int p = nb * 16 + lr;
      int byte = ((p << 9) + ((ks*32 + lg*8) << 1)) ^ ((p & 7) << 4);
      short8 B = *(const short8*)((const char*)sl + byte);
      acc[nb] = __builtin_amdgcn_mfma_f32_16x16x32_bf16(A, B, acc[nb], 0, 0, 0);
    }
  }
  #pragma unroll
  for (int nb = 0; nb < 4; ++nb) {
    int p = p0 + nb*16 + lr;
    if (p < LFIN) {
      #pragma unroll
      for (int r = 0; r < 4; ++r) {
        int co = 16*w + lg*4 + r;
        out[((size_t)n*64 + co) * LFIN + p] = acc[nb][r] + eb[co];
      }
    }
  }
}

// ---------------- host ----------------
extern "C" void kernel_launch(void* const* d_in, const int* in_sizes, int n_in,
                              void* d_out, int out_size, void* d_ws, size_t ws_size,
                              hipStream_t stream)
{
  const float* x      = (const float*)d_in[0];
  const float* startw = (const float*)d_in[1];
  const float* startb = (const float*)d_in[2];
  const float* dilw   = (const float*)d_in[3];
  const float* dilb   = (const float*)d_in[4];
  const float* resw   = (const float*)d_in[5];
  const float* resb   = (const float*)d_in[6];
  const float* skipw  = (const float*)d_in[7];
  const float* skipb  = (const float*)d_in[8];
  const float* endw   = (const float*)d_in[9];
  const float* endb   = (const float*)d_in[10];

  unsigned short* H0 = (unsigned short*)d_ws;       // [8][8192][128] bf16 pos-major
  unsigned short* H1 = H0 + (size_t)8*L0*128;
  float* SK = (float*)(H1 + (size_t)8*L0*128);      // [8][4612][256] f32 pos-major
  unsigned short* Wd = (unsigned short*)(SK + (size_t)8*LFIN*256);
  unsigned short* Wr = Wd + (size_t)39*65536;
  unsigned short* Ws = Wr + (size_t)39*16384;
  unsigned short* We = Ws + (size_t)39*32768;

  const int total = 39*65536 + 39*16384 + 39*32768 + 16384;
  wconv_kernel<<<(total + 255)/256, 256, 0, stream>>>(dilw, resw, skipw, endw, Wd, Wr, Ws, We);
  start_kernel<<<dim3(L0/64, 8), 256, 0, stream>>>(x, startw, startb, H0);

  unsigned short* bufs[2] = {H0, H1};
  int cur = 0, L = L0;
  for (int i = 0; i < 39; ++i) {
    int d = DILS[i];
    int Lout = L - d;
    dim3 grid((Lout + 63) / 64, 8);
    layer_mfma<<<grid, 256, 0, stream>>>(bufs[cur], bufs[cur ^ 1], SK,
        Wd + (size_t)i*65536, dilb + (size_t)i*256,
        Wr + (size_t)i*16384, resb + (size_t)i*128,
        Ws + (size_t)i*32768, skipb + (size_t)i*256,
        d, Lout, i ? 1 : 0);
    cur ^= 1;
    L = Lout;
  }

  end_mfma<<<dim3((LFIN + 63)/64, 8), 256, 0, stream>>>(SK, We, endb, (float*)d_out);
}

// Round 3
// 1973.916 us; speedup vs baseline: 1.9659x; 1.7301x over previous
//
#include <hip/hip_runtime.h>

typedef __attribute__((ext_vector_type(8)))  short short8;
typedef __attribute__((ext_vector_type(4)))  float f32x4;
typedef __attribute__((ext_vector_type(16))) float f32x16;

#define L0    8192
#define LFIN  4612
#define PSKIP 3580   // L0 - LFIN

static const int DILS[39] = {
  1,2,4,8,16,32,64,128,256,512,
  1,2,4,8,16,32,64,128,256,512,
  1,2,4,8,16,32,64,128,256,512,
  1,2,4,8,16,32,64,128,256};

__device__ __forceinline__ unsigned short f2bf(float f) {
  unsigned u = __builtin_bit_cast(unsigned, f);
  u += 0x7fffu + ((u >> 16) & 1u);          // RNE
  return (unsigned short)(u >> 16);
}
__device__ __forceinline__ float bf2f(unsigned short h) {
  return __builtin_bit_cast(float, (unsigned)h << 16);
}

// ---------------- weight conversion f32 -> bf16 (once per call) ----------------
// Wd layout: [layer][co 256][k 256], k = tap*128 + ci  (tap0 @ p-d, tap1 @ p)
__global__ __launch_bounds__(256) void wconv_kernel(
    const float* __restrict__ dw, const float* __restrict__ rw,
    const float* __restrict__ sw, const float* __restrict__ ew,
    unsigned short* __restrict__ Wd, unsigned short* __restrict__ Wr,
    unsigned short* __restrict__ Ws, unsigned short* __restrict__ We)
{
  int e = blockIdx.x * 256 + threadIdx.x;
  const int ND = 39*65536, NR = 39*16384, NS = 39*32768, NE = 16384;
  if (e < ND) {
    int i = e >> 16, r = e & 65535;
    int co = r >> 8, k = r & 255;
    int tap = k >> 7, ci = k & 127;
    Wd[e] = f2bf(dw[(((size_t)i*256 + co)*128 + ci)*2 + tap]);
  } else if ((e -= ND) < NR) {
    Wr[e] = f2bf(rw[e]);
  } else if ((e -= NR) < NS) {
    Ws[e] = f2bf(sw[e]);
  } else if ((e -= NS) < NE) {
    We[e] = f2bf(ew[e]);
  }
}

// ---------------- start: 1x1 conv 40 -> 128, position-major bf16 output ----------------
__global__ __launch_bounds__(256) void start_kernel(
    const float* __restrict__ x, const float* __restrict__ w,
    const float* __restrict__ b, unsigned short* __restrict__ H)
{
  __shared__ float xs[40][64];
  __shared__ float wl[128*41];
  const int tid = threadIdx.x;
  const int n = blockIdx.y;
  const int p0 = blockIdx.x * 64;

  for (int e = tid; e < 40*64; e += 256) {
    int ci = e >> 6, t = e & 63;
    xs[ci][t] = x[((size_t)n*40 + ci)*L0 + p0 + t];
  }
  for (int e = tid; e < 128*40; e += 256)
    wl[(e/40)*41 + (e%40)] = w[e];
  __syncthreads();

  const int c  = tid & 127;
  const int ph = tid >> 7;                 // 0..1
  const float bias = b[c];
  #pragma unroll 4
  for (int k = 0; k < 32; ++k) {
    int p = ph + 2*k;
    float acc = bias;
    #pragma unroll
    for (int ci = 0; ci < 40; ++ci)
      acc = fmaf(wl[c*41 + ci], xs[ci][p], acc);
    H[((size_t)n*L0 + p0 + p)*128 + c] = f2bf(acc);
  }
}

// ---------------- one gated residual layer, 32x32x16 MFMA ----------------
// H: bf16 position-major [n][8192][128], right-aligned.
// taps LDS [64 p][256 k] bf16, swizzled: byte = (p*512 + 2k) ^ ((p&7)<<4)
// Round-0 layout throughout (A = weights, D[co regs][p lanes]) -- 84-VGPR proven.
// Block swizzle: n = lb&7, x = lb>>3  =>  each batch pinned to one XCD;
// that batch's whole H buffer (2.1 MB bf16) is L2-resident on that XCD.
__global__ __launch_bounds__(256) void layer_mfma(
    const unsigned short* __restrict__ Hin, unsigned short* __restrict__ Hout,
    float* __restrict__ SK,
    const unsigned short* __restrict__ Wd, const float* __restrict__ db,
    const unsigned short* __restrict__ Wr, const float* __restrict__ rb,
    const unsigned short* __restrict__ Ws, const float* __restrict__ sb,
    int d, int Lout, int accum)
{
  __shared__ unsigned short taps[64*256];   // 32 KiB

  const int tid = threadIdx.x;
  const int lb = blockIdx.x + gridDim.x * blockIdx.y;   // linear id, x fastest
  const int n  = lb & 7;                                // batch -> XCD
  const int bx = lb >> 3;                               // position tile
  const int p0 = (L0 - Lout) + bx * 64;
  const unsigned short* __restrict__ Hn = Hin + (size_t)n * L0 * 128;

  const int w  = tid >> 6, lane = tid & 63;
  const int ln = lane & 31, hi = lane >> 5;

  // ---- stage taps: global bf16 -> LDS (swizzled), 16B per lane ----
  #pragma unroll
  for (int it = 0; it < 8; ++it) {
    int e = it * 256 + tid;          // 0..2047
    int c8  = (e & 15) << 3;         // ci 0..120 step 8
    int p   = (e >> 4) & 63;
    int tap = e >> 10;
    int gp = p0 + p - (tap ? 0 : d);
    if (gp > L0 - 1) gp = L0 - 1;    // p0 >= d always, so gp >= 0
    short8 v = *(const short8*)&Hn[(size_t)gp * 128 + c8];
    int byte = ((p << 9) + (((tap << 7) + c8) << 1)) ^ ((p & 7) << 4);
    *(short8*)((char*)taps + byte) = v;
  }

  // ---- prefetch first 4 k-steps of GEMM1 weights before the barrier ----
  short8 pwf[4], pwg[4];
  #pragma unroll
  for (int j = 0; j < 4; ++j) {
    pwf[j] = *(const short8*)&Wd[(size_t)(32*w + ln) * 256 + j*16 + hi*8];
    pwg[j] = *(const short8*)&Wd[(size_t)(128 + 32*w + ln) * 256 + j*16 + hi*8];
  }
  __syncthreads();

  const f32x16 fz16 = {0.f};

  // ---- GEMM1: dilated conv, D[256co regs][64p lanes], K=256 ----
  f32x16 af[2] = {fz16, fz16}, ag[2] = {fz16, fz16};
  #pragma unroll
  for (int ks = 0; ks < 16; ++ks) {
    int kb = ks*32 + hi*16;                     // byte offset of k-chunk
    int pA = ln, pB = 32 + ln;
    short8 B0 = *(const short8*)((const char*)taps + (((pA << 9) + kb) ^ ((pA & 7) << 4)));
    short8 B1 = *(const short8*)((const char*)taps + (((pB << 9) + kb) ^ ((pB & 7) << 4)));
    short8 Af = (ks < 4) ? pwf[ks]
              : *(const short8*)&Wd[(size_t)(32*w + ln) * 256 + ks*16 + hi*8];
    short8 Ag = (ks < 4) ? pwg[ks]
              : *(const short8*)&Wd[(size_t)(128 + 32*w + ln) * 256 + ks*16 + hi*8];
    af[0] = __builtin_amdgcn_mfma_f32_32x32x16_bf16(Af, B0, af[0], 0, 0, 0);
    af[1] = __builtin_amdgcn_mfma_f32_32x32x16_bf16(Af, B1, af[1], 0, 0, 0);
    ag[0] = __builtin_amdgcn_mfma_f32_32x32x16_bf16(Ag, B0, ag[0], 0, 0, 0);
    ag[1] = __builtin_amdgcn_mfma_f32_32x32x16_bf16(Ag, B1, ag[1], 0, 0, 0);
  }

  // ---- gate in registers; D row(co) = (reg&3)+8*(reg>>2)+4*hi, col(p) = ln ----
  __syncthreads();     // all waves done reading taps (tap0 about to be overwritten)
  #pragma unroll
  for (int nb = 0; nb < 2; ++nb) {
    int p = nb*32 + ln;
    #pragma unroll
    for (int q = 0; q < 4; ++q) {
      int rbase = 8*q + 4*hi;
      const float4 bf4 = *(const float4*)&db[32*w + rbase];
      const float4 bg4 = *(const float4*)&db[128 + 32*w + rbase];
      const float bfv[4] = {bf4.x, bf4.y, bf4.z, bf4.w};
      const float bgv[4] = {bg4.x, bg4.y, bg4.z, bg4.w};
      unsigned short gs[4];
      #pragma unroll
      for (int r = 0; r < 4; ++r) {
        float fv = af[nb][4*q + r] + bfv[r];
        float gg = ag[nb][4*q + r] + bgv[r];
        float th = 2.f * __builtin_amdgcn_rcpf(1.f + __expf(-2.f * fv)) - 1.f;
        float sg = __builtin_amdgcn_rcpf(1.f + __expf(-gg));
        gs[r] = f2bf(th * sg);
      }
      ushort4 gv; gv.x = gs[0]; gv.y = gs[1]; gv.z = gs[2]; gv.w = gs[3];
      int byte = ((p << 9) + ((32*w + rbase) << 1)) ^ ((p & 7) << 4);
      *(ushort4*)((char*)taps + byte) = gv;
    }
  }
  __syncthreads();

  // ---- load all gated B fragments (K=128 -> 8 ks), reused by 3 output passes ----
  short8 Bg[2][8];
  #pragma unroll
  for (int nb = 0; nb < 2; ++nb) {
    int p = nb*32 + ln;
    #pragma unroll
    for (int ks = 0; ks < 8; ++ks)
      Bg[nb][ks] = *(const short8*)((const char*)taps +
                     (((p << 9) + ks*32 + hi*16) ^ ((p & 7) << 4)));
  }

  float* SKn = SK + (size_t)n * LFIN * 256;
  unsigned short* Hon = Hout + (size_t)n * L0 * 128;

  // ---- passes 0,1: skip co = 32w+128t (elided if block entirely below PSKIP) ----
  if (p0 + 63 >= PSKIP) {
    #pragma unroll
    for (int t = 0; t < 2; ++t) {
      const unsigned short* Aw = Ws + (size_t)(32*w + 128*t) * 128;
      f32x16 acc[2] = {fz16, fz16};
      #pragma unroll
      for (int ks = 0; ks < 8; ++ks) {
        short8 A = *(const short8*)&Aw[(size_t)ln * 128 + ks*16 + hi*8];
        acc[0] = __builtin_amdgcn_mfma_f32_32x32x16_bf16(A, Bg[0][ks], acc[0], 0, 0, 0);
        acc[1] = __builtin_amdgcn_mfma_f32_32x32x16_bf16(A, Bg[1][ks], acc[1], 0, 0, 0);
      }
      #pragma unroll
      for (int nb = 0; nb < 2; ++nb) {
        int p = p0 + nb*32 + ln;
        if (p >= PSKIP && p < L0) {
          #pragma unroll
          for (int q = 0; q < 4; ++q) {
            int co = 32*w + 128*t + 8*q + 4*hi;
            const float4 sb4 = *(const float4*)&sb[co];
            float* dst = &SKn[(size_t)(p - PSKIP) * 256 + co];
            float4 v = make_float4(acc[nb][4*q]   + sb4.x, acc[nb][4*q+1] + sb4.y,
                                   acc[nb][4*q+2] + sb4.z, acc[nb][4*q+3] + sb4.w);
            if (accum) {
              float4 o = *(const float4*)dst;
              v.x += o.x; v.y += o.y; v.z += o.z; v.w += o.w;
            }
            *(float4*)dst = v;
          }
        }
      }
    }
  }
  // ---- pass 2: res co = 32w ----
  {
    const unsigned short* Aw = Wr + (size_t)(32*w) * 128;
    f32x16 acc[2] = {fz16, fz16};
    #pragma unroll
    for (int ks = 0; ks < 8; ++ks) {
      short8 A = *(const short8*)&Aw[(size_t)ln * 128 + ks*16 + hi*8];
      acc[0] = __builtin_amdgcn_mfma_f32_32x32x16_bf16(A, Bg[0][ks], acc[0], 0, 0, 0);
      acc[1] = __builtin_amdgcn_mfma_f32_32x32x16_bf16(A, Bg[1][ks], acc[1], 0, 0, 0);
    }
    #pragma unroll
    for (int nb = 0; nb < 2; ++nb) {
      int pl = nb*32 + ln;
      int p = p0 + pl;
      if (p < L0) {
        #pragma unroll
        for (int q = 0; q < 4; ++q) {
          int co = 32*w + 8*q + 4*hi;
          const float4 rb4 = *(const float4*)&rb[co];
          // residual from LDS tap1 (bf16 H at position p)
          ushort4 hv = *(const ushort4*)((const char*)taps +
                         (((pl << 9) + ((128 + co) << 1)) ^ ((pl & 7) << 4)));
          ushort4 hb;
          hb.x = f2bf(acc[nb][4*q]   + rb4.x + bf2f(hv.x));
          hb.y = f2bf(acc[nb][4*q+1] + rb4.y + bf2f(hv.y));
          hb.z = f2bf(acc[nb][4*q+2] + rb4.z + bf2f(hv.z));
          hb.w = f2bf(acc[nb][4*q+3] + rb4.w + bf2f(hv.w));
          *(ushort4*)&Hon[(size_t)p * 128 + co] = hb;
        }
      }
    }
  }
}

// ---------------- end: relu + 1x1 conv 256 -> 64 (16x16 MFMA) ----------------
__global__ __launch_bounds__(256) void end_mfma(
    const float* __restrict__ SK, const unsigned short* __restrict__ We,
    const float* __restrict__ eb, float* __restrict__ out)
{
  __shared__ unsigned short sl[64*256];
  const int tid = threadIdx.x;
  const int n = blockIdx.y;
  const int p0 = blockIdx.x * 64;
  const float* __restrict__ SKn = SK + (size_t)n * LFIN * 256;

  #pragma unroll
  for (int it = 0; it < 16; ++it) {
    int e = it * 256 + tid;
    int c4 = (e & 63) << 2;
    int p  = e >> 6;
    int gp = p0 + p; if (gp > LFIN - 1) gp = LFIN - 1;
    float4 v = *(const float4*)&SKn[(size_t)gp * 256 + c4];
    ushort4 h;
    h.x = f2bf(fmaxf(v.x, 0.f)); h.y = f2bf(fmaxf(v.y, 0.f));
    h.z = f2bf(fmaxf(v.z, 0.f)); h.w = f2bf(fmaxf(v.w, 0.f));
    int byte = ((p << 9) + (c4 << 1)) ^ ((p & 7) << 4);
    *(ushort4*)((char*)sl + byte) = h;
  }
  __syncthreads();

  const int w  = tid >> 6, lane = tid & 63;
  const int lr = lane & 15, lg = lane >> 4;
  const f32x4 fz = {0.f, 0.f, 0.f, 0.f};
  f32x4 acc[4] = {fz, fz, fz, fz};

  #pragma unroll
  for (int ks = 0; ks < 8; ++ks) {
    short8 A = *(const short8*)&We[(size_t)(16*w + lr) * 256 + ks*32 + lg*8];
    #pragma unroll
    for (int nb = 0; nb < 4; ++nb) {
      int p = nb * 16 + lr;
      int byte = ((p << 9) + ((ks*32 + lg*8) << 1)) ^ ((p & 7) << 4);
      short8 B = *(const short8*)((const char*)sl + byte);
      acc[nb] = __builtin_amdgcn_mfma_f32_16x16x32_bf16(A, B, acc[nb], 0, 0, 0);
    }
  }
  #pragma unroll
  for (int nb = 0; nb < 4; ++nb) {
    int p = p0 + nb*16 + lr;
    if (p < LFIN) {
      #pragma unroll
      for (int r = 0; r < 4; ++r) {
        int co = 16*w + lg*4 + r;
        out[((size_t)n*64 + co) * LFIN + p] = acc[nb][r] + eb[co];
      }
    }
  }
}

// ---------------- host ----------------
extern "C" void kernel_launch(void* const* d_in, const int* in_sizes, int n_in,
                              void* d_out, int out_size, void* d_ws, size_t ws_size,
                              hipStream_t stream)
{
  const float* x      = (const float*)d_in[0];
  const float* startw = (const float*)d_in[1];
  const float* startb = (const float*)d_in[2];
  const float* dilw   = (const float*)d_in[3];
  const float* dilb   = (const float*)d_in[4];
  const float* resw   = (const float*)d_in[5];
  const float* resb   = (const float*)d_in[6];
  const float* skipw  = (const float*)d_in[7];
  const float* skipb  = (const float*)d_in[8];
  const float* endw   = (const float*)d_in[9];
  const float* endb   = (const float*)d_in[10];

  unsigned short* H0 = (unsigned short*)d_ws;       // [8][8192][128] bf16 pos-major
  unsigned short* H1 = H0 + (size_t)8*L0*128;
  float* SK = (float*)(H1 + (size_t)8*L0*128);      // [8][4612][256] f32 pos-major
  unsigned short* Wd = (unsigned short*)(SK + (size_t)8*LFIN*256);
  unsigned short* Wr = Wd + (size_t)39*65536;
  unsigned short* Ws = Wr + (size_t)39*16384;
  unsigned short* We = Ws + (size_t)39*32768;

  const int total = 39*65536 + 39*16384 + 39*32768 + 16384;
  wconv_kernel<<<(total + 255)/256, 256, 0, stream>>>(dilw, resw, skipw, endw, Wd, Wr, Ws, We);
  start_kernel<<<dim3(L0/64, 8), 256, 0, stream>>>(x, startw, startb, H0);

  unsigned short* bufs[2] = {H0, H1};
  int cur = 0, L = L0;
  for (int i = 0; i < 39; ++i) {
    int d = DILS[i];
    int Lout = L - d;
    dim3 grid((Lout + 63) / 64, 8);
    layer_mfma<<<grid, 256, 0, stream>>>(bufs[cur], bufs[cur ^ 1], SK,
        Wd + (size_t)i*65536, dilb + (size_t)i*256,
        Wr + (size_t)i*16384, resb + (size_t)i*128,
        Ws + (size_t)i*32768, skipb + (size_t)i*256,
        d, Lout, i ? 1 : 0);
    cur ^= 1;
    L = Lout;
  }

  end_mfma<<<dim3((LFIN + 63)/64, 8), 256, 0, stream>>>(SK, We, endb, (float*)d_out);
}